// Round 13
// baseline (886.174 us; speedup 1.0000x reference)
//
#include <hip/hip_runtime.h>
#include <hip/hip_bf16.h>
#include <cstdint>

#define N_NODES 100000
#define N_EDGES 1600000
#define C_IN    10
#define C_H     128
#define LN_EPS  1e-5f

#define SCAN_BLOCKS 98   // ceil(N_NODES / 1024)

// ---------------------------------------------------------------------------
// bf16 helpers.  All aggregated values are >= 0 (post-ReLU h; nf = sum of
// o*sigmoid >= 0), so bf16 numeric max == unsigned 16-bit integer max on the
// raw bit patterns, and a packed u16x2 max does both channels in one VALU op.
// ---------------------------------------------------------------------------
typedef unsigned short u16x2 __attribute__((ext_vector_type(2)));

static __device__ inline unsigned pkmax(unsigned a, unsigned b) {
    u16x2 x = __builtin_bit_cast(u16x2, a), y = __builtin_bit_cast(u16x2, b);
    return __builtin_bit_cast(unsigned, __builtin_elementwise_max(x, y));
}
static __device__ inline unsigned bf16rne(float f) {          // round-to-nearest-even
    unsigned u = __float_as_uint(f);
    return (u + 0x7FFFu + ((u >> 16) & 1u)) >> 16;
}
static __device__ inline unsigned packbf(float lo, float hi) { // lo=ch 2l, hi=ch 2l+1
    return (bf16rne(hi) << 16) | bf16rne(lo);
}
// Non-temporal gather load: the 25.6MB random row set has zero L1 reuse;
// nt spares L1 lines/MSHRs for the pack/residual streams.
static __device__ inline unsigned ldnt(const unsigned* p) {
    return __builtin_nontemporal_load(p);
}

// ---------------------------------------------------------------------------
// CSR build: histogram of dst (total + poly), two-level exclusive scan,
// scatter with poly edges placed FIRST within each node's segment.
// ---------------------------------------------------------------------------
__global__ void hist_kernel(const int* __restrict__ dst, const int* __restrict__ attr,
                            int* __restrict__ cnt, int* __restrict__ pcnt) {
    int i = blockIdx.x * blockDim.x + threadIdx.x;
    int stride = gridDim.x * blockDim.x;
    for (; i < N_EDGES; i += stride) {
        int d = dst[i];
        atomicAdd(&cnt[d], 1);
        if (attr[i] == 3) atomicAdd(&pcnt[d], 1);
    }
}

__device__ inline int wave_incl_scan(int v, int lane) {
#pragma unroll
    for (int off = 1; off < 64; off <<= 1) {
        int n = __shfl_up(v, off);
        if (lane >= off) v += n;
    }
    return v;
}

__global__ __launch_bounds__(1024) void scan1_kernel(const int* __restrict__ cnt,
                                                     int* __restrict__ excl,
                                                     int* __restrict__ bsum) {
    __shared__ int wsum[16];
    const int t = threadIdx.x, lane = t & 63, wid = t >> 6;
    const int i = blockIdx.x * 1024 + t;
    const int v = (i < N_NODES) ? cnt[i] : 0;
    int inc = wave_incl_scan(v, lane);
    if (lane == 63) wsum[wid] = inc;
    __syncthreads();
    if (t < 16) {
        int w = wsum[t];
#pragma unroll
        for (int off = 1; off < 16; off <<= 1) {
            int n = __shfl_up(w, off);
            if (t >= off) w += n;
        }
        wsum[t] = w;
    }
    __syncthreads();
    const int woff = (wid == 0) ? 0 : wsum[wid - 1];
    if (i < N_NODES) excl[i] = inc - v + woff;
    if (t == 0) bsum[blockIdx.x] = wsum[15];
}

__global__ void scan2_kernel(const int* __restrict__ bsum, int* __restrict__ bofs) {
    __shared__ int wsum[2];
    const int t = threadIdx.x, lane = t & 63, wid = t >> 6;
    const int v = (t < SCAN_BLOCKS) ? bsum[t] : 0;
    int inc = wave_incl_scan(v, lane);
    if (lane == 63) wsum[wid] = inc;
    __syncthreads();
    const int woff = (wid == 0) ? 0 : wsum[0];
    if (t < SCAN_BLOCKS) bofs[t] = inc - v + woff;
}

__global__ __launch_bounds__(1024) void scan3_kernel(const int* __restrict__ excl,
                                                     const int* __restrict__ bofs,
                                                     const int* __restrict__ pcnt,
                                                     int* __restrict__ row_off,
                                                     int* __restrict__ poly_end) {
    const int i = blockIdx.x * 1024 + threadIdx.x;
    if (i < N_NODES) {
        const int r = excl[i] + bofs[blockIdx.x];
        row_off[i]  = r;
        poly_end[i] = r + pcnt[i];
    }
    if (i == 0) row_off[N_NODES] = N_EDGES;
}

__global__ void scatter_kernel(const int* __restrict__ src, const int* __restrict__ dst,
                               const int* __restrict__ attr,
                               const int* __restrict__ row_off, const int* __restrict__ poly_end,
                               int* __restrict__ curP, int* __restrict__ curR,
                               int* __restrict__ pack) {
    int i = blockIdx.x * blockDim.x + threadIdx.x;
    int stride = gridDim.x * blockDim.x;
    for (; i < N_EDGES; i += stride) {
        int d = dst[i];
        int pos;
        if (attr[i] == 3) pos = row_off[d]  + atomicAdd(&curP[d], 1);
        else              pos = poly_end[d] + atomicAdd(&curR[d], 1);
        pack[pos] = src[i];  // order within a segment is nondeterministic; max is invariant
    }
}

// ---------------------------------------------------------------------------
// Input projection: h0 = relu(x @ W_in^T + b_in), plus a bf16 shadow h16 for
// the next layer's gather.  One wave per node; lane l owns channels (2l,2l+1).
// ---------------------------------------------------------------------------
__global__ void in_proj_kernel(const float* __restrict__ x, const float* __restrict__ Win,
                               const float* __restrict__ bin, float* __restrict__ h0,
                               unsigned* __restrict__ h16) {
    __shared__ float Wl[C_H * 11];
    for (int i = threadIdx.x; i < C_H * C_IN; i += blockDim.x) {
        int c = i / C_IN, k = i % C_IN;
        Wl[c * 11 + k] = Win[i];
    }
    __syncthreads();
    const int l = threadIdx.x & 63, wid = threadIdx.x >> 6;
    const int wave = blockIdx.x * 4 + wid, nw = gridDim.x * 4;
    const float2 bb = *reinterpret_cast<const float2*>(bin + 2 * l);
    for (int n = wave; n < N_NODES; n += nw) {
        float xr[C_IN];
#pragma unroll
        for (int k = 0; k < C_IN; ++k) xr[k] = x[n * C_IN + k];  // wave-uniform
        float a0 = bb.x, a1 = bb.y;
#pragma unroll
        for (int k = 0; k < C_IN; ++k) {
            a0 = fmaf(xr[k], Wl[(2 * l) * 11 + k], a0);
            a1 = fmaf(xr[k], Wl[(2 * l + 1) * 11 + k], a1);
        }
        a0 = fmaxf(a0, 0.f);
        a1 = fmaxf(a1, 0.f);
        *reinterpret_cast<float2*>(h0 + (size_t)n * C_H + 2 * l) = make_float2(a0, a1);
        h16[(size_t)n * 64 + l] = packbf(a0, a1);
    }
}

// ---------------------------------------------------------------------------
// Fused MPNN layer: bf16 gather-max -> fp32 GEMM -> LN -> residual ReLU.
// MODE 0: hop0  (hout+hout16, nf  = o*sg)
// MODE 1: hop1  (hout+hout16, nf += o*sg)
// MODE 2: hop2  (no hout; nf += o*sg, write nf16 (=hout16), v3 reduction)
// MODE 3: final (no writes; poly-only agg; v2 reduction; residual = nf)
//
// == R9 configuration verbatim (session best: 762 us) + NT gather loads ==
// 1024-thread block = 16 waves, ONE LDS W copy (fp32, 64 KB, swizzle key
// (c>>1)&31 so lane l's rows 2l,2l+1 read conflict-free) + aggU 16 KB
// (packed bf16 agg) = 80 KB.
// Gather: ONE uint per lane per edge (channels 2l,2l+1 packed bf16); a wave
// load covers the full 256B row.  pk-u16 max (values >= 0).  Depth 8/4/2/1.
// Session evidence: 6 configs (fp32/bf16 rows, 4096-16384 waves, VALU
// 14-58%) all deliver 8-10G random-row requests/s -> request-rate wall.
// ---------------------------------------------------------------------------
#define NPW 4
#define LWAVES 16

template <int MODE>
__global__ __launch_bounds__(1024) void layer_kernel(
    const float* __restrict__ hin, const unsigned* __restrict__ hin16,
    float* __restrict__ hout, unsigned* __restrict__ hout16,
    float* __restrict__ nf, const float* __restrict__ x,
    const int* __restrict__ row_off, const int* __restrict__ poly_end,
    const int* __restrict__ pack,
    const float* __restrict__ W, const float* __restrict__ bias,
    const float* __restrict__ gamma, const float* __restrict__ beta,
    const float* __restrict__ gate, float* __restrict__ out)
{
    __shared__ float    Wl[C_H * C_H];             // 64 KB, swizzle key (c>>1)&31
    __shared__ unsigned aggU[LWAVES][NPW * 64];    // 16 KB, packed bf16 agg rows

    for (int i = threadIdx.x; i < C_H * C_H; i += 1024) {
        int c = i >> 7, k = i & 127;
        Wl[(c << 7) + (k ^ ((c >> 1) & 31))] = W[i];   // conflict-free write
    }
    __syncthreads();

    const int l = threadIdx.x & 63, wid = threadIdx.x >> 6;
    const int swz = l & 31;
    const int row0 = (2 * l) << 7, row1 = (2 * l + 1) << 7;
    const int wave = blockIdx.x * LWAVES + wid, nw = gridDim.x * LWAVES;

    const float2 bb = *reinterpret_cast<const float2*>(bias  + 2 * l);
    const float2 gg = *reinterpret_cast<const float2*>(gamma + 2 * l);
    const float2 ee = *reinterpret_cast<const float2*>(beta  + 2 * l);
    float sg0 = 0.f, sg1 = 0.f;
    if (MODE <= 2) {
        const float2 gt = *reinterpret_cast<const float2*>(gate + 2 * l);
        sg0 = 1.f / (1.f + expf(-gt.x));
        sg1 = 1.f / (1.f + expf(-gt.y));
    }

    float red0 = 0.f, red1 = 0.f;                  // v2/v3 per-wave partial max (>= 0)

    const unsigned* __restrict__ hb16 = hin16 + l;

    for (int base = wave * NPW; base < N_NODES; base += nw * NPW) {
        bool anyp[NPW];
        // ---- aggregation: packed-bf16 CSR segment max, depth ladder 8/4/2/1 ----
#pragma unroll
        for (int j = 0; j < NPW; ++j) {
            const int n = base + j;
            unsigned m = 0u;                       // bf16 {0,0}; "no incoming" -> 0
            bool ap = false;
            if (n < N_NODES) {
                const int beg = row_off[n];
                const int end = (MODE == 3) ? poly_end[n] : row_off[n + 1];
                ap = (end > beg);
                int e = beg;
                for (; e + 8 <= end; e += 8) {
                    unsigned v[8];
#pragma unroll
                    for (int t = 0; t < 8; ++t)
                        v[t] = ldnt(&hb16[(size_t)pack[e + t] * 64]);
#pragma unroll
                    for (int t = 0; t < 8; ++t) m = pkmax(m, v[t]);
                }
                for (; e + 4 <= end; e += 4) {
                    const unsigned v0 = ldnt(&hb16[(size_t)pack[e]     * 64]);
                    const unsigned v1 = ldnt(&hb16[(size_t)pack[e + 1] * 64]);
                    const unsigned v2 = ldnt(&hb16[(size_t)pack[e + 2] * 64]);
                    const unsigned v3 = ldnt(&hb16[(size_t)pack[e + 3] * 64]);
                    m = pkmax(m, pkmax(pkmax(v0, v1), pkmax(v2, v3)));
                }
                for (; e + 2 <= end; e += 2) {
                    const unsigned v0 = ldnt(&hb16[(size_t)pack[e]     * 64]);
                    const unsigned v1 = ldnt(&hb16[(size_t)pack[e + 1] * 64]);
                    m = pkmax(m, pkmax(v0, v1));
                }
                if (e < end) m = pkmax(m, ldnt(&hb16[(size_t)pack[e] * 64]));
            }
            anyp[j] = ap;
            aggU[wid][j * 64 + l] = m;             // wave-private, no barrier needed
        }

        // ---- GEMM: out[c] = sum_k agg[k] * W[c][k], 2 cols per packed agg ----
        float acc[NPW][2];
#pragma unroll
        for (int j = 0; j < NPW; ++j) { acc[j][0] = 0.f; acc[j][1] = 0.f; }
#pragma unroll 4
        for (int t = 0; t < 64; ++t) {
            const int c0 = (2 * t) ^ swz, c1 = (2 * t + 1) ^ swz;  // swizzled cols
            const float w00 = Wl[row0 + c0], w01 = Wl[row0 + c1];  // W[2l][2t], W[2l][2t+1]
            const float w10 = Wl[row1 + c0], w11 = Wl[row1 + c1];  // W[2l+1][..]
#pragma unroll
            for (int j = 0; j < NPW; ++j) {
                const unsigned u = aggU[wid][j * 64 + t];          // broadcast
                const float a0 = __uint_as_float(u << 16);         // ch 2t
                const float a1 = __uint_as_float(u & 0xFFFF0000u); // ch 2t+1
                acc[j][0] = fmaf(a1, w01, fmaf(a0, w00, acc[j][0]));
                acc[j][1] = fmaf(a1, w11, fmaf(a0, w10, acc[j][1]));
            }
        }

        // ---- epilogue: bias, LN, residual relu, nf/v-reductions ----
#pragma unroll
        for (int j = 0; j < NPW; ++j) {
            const int n = base + j;
            if (n < N_NODES) {               // wave-uniform branch
                float h0 = acc[j][0] + bb.x, h1 = acc[j][1] + bb.y;  // ch 2l, 2l+1
                float s = h0 + h1, q = h0 * h0 + h1 * h1;
#pragma unroll
                for (int m2 = 1; m2 < 64; m2 <<= 1) {
                    s += __shfl_xor(s, m2);
                    q += __shfl_xor(q, m2);
                }
                const float mu  = s * (1.f / 128.f);
                const float var = q * (1.f / 128.f) - mu * mu;   // biased var
                const float rs  = rsqrtf(var + LN_EPS);
                const float2 r = *reinterpret_cast<const float2*>(hin + (size_t)n * C_H + 2 * l);
                const float o0 = fmaxf((h0 - mu) * rs * gg.x + ee.x + r.x, 0.f);
                const float o1 = fmaxf((h1 - mu) * rs * gg.y + ee.y + r.y, 0.f);
                if (MODE <= 1) {
                    *reinterpret_cast<float2*>(hout + (size_t)n * C_H + 2 * l) = make_float2(o0, o1);
                    hout16[(size_t)n * 64 + l] = packbf(o0, o1);
                }
                if (MODE == 0) {
                    *reinterpret_cast<float2*>(nf + (size_t)n * C_H + 2 * l) =
                        make_float2(o0 * sg0, o1 * sg1);
                } else if (MODE == 1) {
                    float2* p = reinterpret_cast<float2*>(nf + (size_t)n * C_H + 2 * l);
                    float2 v = *p;
                    v.x += o0 * sg0; v.y += o1 * sg1;
                    *p = v;
                } else if (MODE == 2) {
                    float2* p = reinterpret_cast<float2*>(nf + (size_t)n * C_H + 2 * l);
                    float2 v = *p;
                    const float f0 = v.x + o0 * sg0, f1 = v.y + o1 * sg1;
                    *p = make_float2(f0, f1);
                    hout16[(size_t)n * 64 + l] = packbf(f0, f1);   // nf16 for MODE 3
                    if (x[(size_t)n * C_IN] <= 0.1f) {             // rem = !(x0 > 0.1)
                        red0 = fmaxf(red0, f0);
                        red1 = fmaxf(red1, f1);
                    }
                } else {                                            // MODE 3
                    if (anyp[j]) {                                  // sink node
                        red0 = fmaxf(red0, o0);
                        red1 = fmaxf(red1, o1);
                    }
                }
            }
        }
    }

    if (MODE >= 2) {
        __syncthreads();
        float* red = reinterpret_cast<float*>(&aggU[0][0]);  // alias (16 KB >= 8 KB)
        *reinterpret_cast<float2*>(&red[wid * 128 + 2 * l]) = make_float2(red0, red1);
        __syncthreads();
        if (threadIdx.x < 128) {
            const int c = threadIdx.x;
            float m = red[c];
#pragma unroll
            for (int w = 1; w < LWAVES; ++w) m = fmaxf(m, red[w * 128 + c]);
            float* o = out + (MODE == 3 ? 0 : 128);
            atomicMax(reinterpret_cast<int*>(o + c), __float_as_int(m));  // m >= 0
        }
    }
}

// ---------------------------------------------------------------------------
extern "C" void kernel_launch(void* const* d_in, const int* in_sizes, int n_in,
                              void* d_out, int out_size, void* d_ws, size_t ws_size,
                              hipStream_t stream) {
    const float* x      = (const float*)d_in[0];
    const float* W_in   = (const float*)d_in[1];
    const float* b_in   = (const float*)d_in[2];
    const float* hop_W  = (const float*)d_in[3];
    const float* hop_b  = (const float*)d_in[4];
    const float* hop_g  = (const float*)d_in[5];
    const float* hop_be = (const float*)d_in[6];
    const float* gates  = (const float*)d_in[7];
    const float* fW     = (const float*)d_in[8];
    const float* fb     = (const float*)d_in[9];
    const float* fg     = (const float*)d_in[10];
    const float* fbe    = (const float*)d_in[11];
    const int*   eidx   = (const int*)d_in[12];
    const int*   eattr  = (const int*)d_in[13];
    float* out = (float*)d_out;

    char* ws = (char*)d_ws;
    size_t off = 0;
    auto alloc = [&](size_t bytes) {
        char* p = ws + off;
        off = (off + bytes + 255) & ~(size_t)255;
        return p;
    };
    const size_t npad = ((size_t)N_NODES * 4 + 255) & ~(size_t)255;
    int*      cnt     = (int*)alloc((size_t)N_NODES * 4);
    int*      pcnt    = (int*)alloc((size_t)N_NODES * 4);
    int*      curP    = (int*)alloc((size_t)N_NODES * 4);
    int*      curR    = (int*)alloc((size_t)N_NODES * 4);
    int*      excl    = (int*)alloc((size_t)N_NODES * 4);
    int*      bsum    = (int*)alloc((size_t)SCAN_BLOCKS * 4);
    int*      bofs    = (int*)alloc((size_t)SCAN_BLOCKS * 4);
    int*      row_off = (int*)alloc((size_t)(N_NODES + 1) * 4);
    int*      polyend = (int*)alloc((size_t)N_NODES * 4);
    int*      pack    = (int*)alloc((size_t)N_EDGES * 4);
    float*    hA      = (float*)alloc((size_t)N_NODES * C_H * 4);
    float*    hB      = (float*)alloc((size_t)N_NODES * C_H * 4);
    float*    nf      = (float*)alloc((size_t)N_NODES * C_H * 4);
    unsigned* hA16    = (unsigned*)alloc((size_t)N_NODES * 64 * 4);
    unsigned* hB16    = (unsigned*)alloc((size_t)N_NODES * 64 * 4);
    unsigned* nf16    = hB16;   // alias: hB16 is dead after MODE 1 reads it
    (void)ws_size;

    const int* src = eidx;
    const int* dst = eidx + N_EDGES;

    // cnt..curR are contiguous padded allocs: one memset covers all four
    hipMemsetAsync(cnt, 0, npad * 4, stream);
    hipMemsetAsync(d_out, 0, 256 * 4, stream);   // v2/v3 accumulate via atomicMax (vals >= 0)

    hist_kernel<<<2048, 256, 0, stream>>>(dst, eattr, cnt, pcnt);
    scan1_kernel<<<SCAN_BLOCKS, 1024, 0, stream>>>(cnt, excl, bsum);
    scan2_kernel<<<1, 128, 0, stream>>>(bsum, bofs);
    scan3_kernel<<<SCAN_BLOCKS, 1024, 0, stream>>>(excl, bofs, pcnt, row_off, polyend);
    scatter_kernel<<<2048, 256, 0, stream>>>(src, dst, eattr, row_off, polyend, curP, curR, pack);
    in_proj_kernel<<<2048, 256, 0, stream>>>(x, W_in, b_in, hA, hA16);

    layer_kernel<0><<<512, 1024, 0, stream>>>(hA, hA16, hB, hB16, nf, x, row_off, polyend, pack,
                                              hop_W + 0 * C_H * C_H, hop_b + 0 * C_H,
                                              hop_g + 0 * C_H, hop_be + 0 * C_H,
                                              gates + 0 * C_H, out);
    layer_kernel<1><<<512, 1024, 0, stream>>>(hB, hB16, hA, hA16, nf, x, row_off, polyend, pack,
                                              hop_W + 1 * C_H * C_H, hop_b + 1 * C_H,
                                              hop_g + 1 * C_H, hop_be + 1 * C_H,
                                              gates + 1 * C_H, out);
    layer_kernel<2><<<512, 1024, 0, stream>>>(hA, hA16, nullptr, nf16, nf, x, row_off, polyend, pack,
                                              hop_W + 2 * C_H * C_H, hop_b + 2 * C_H,
                                              hop_g + 2 * C_H, hop_be + 2 * C_H,
                                              gates + 2 * C_H, out);
    layer_kernel<3><<<512, 1024, 0, stream>>>(nf, nf16, nullptr, nullptr, nullptr, x, row_off, polyend, pack,
                                              fW, fb, fg, fbe, nullptr, out);
}

// Round 14
// 762.229 us; speedup vs baseline: 1.1626x; 1.1626x over previous
//
#include <hip/hip_runtime.h>
#include <hip/hip_bf16.h>
#include <cstdint>

#define N_NODES 100000
#define N_EDGES 1600000
#define C_IN    10
#define C_H     128
#define LN_EPS  1e-5f

#define SCAN_BLOCKS 98   // ceil(N_NODES / 1024)

// ---------------------------------------------------------------------------
// bf16 helpers.  All aggregated values are >= 0 (post-ReLU h; nf = sum of
// o*sigmoid >= 0), so bf16 numeric max == unsigned 16-bit integer max on the
// raw bit patterns, and a packed u16x2 max does both channels in one VALU op.
// ---------------------------------------------------------------------------
typedef unsigned short u16x2 __attribute__((ext_vector_type(2)));

static __device__ inline unsigned pkmax(unsigned a, unsigned b) {
    u16x2 x = __builtin_bit_cast(u16x2, a), y = __builtin_bit_cast(u16x2, b);
    return __builtin_bit_cast(unsigned, __builtin_elementwise_max(x, y));
}
static __device__ inline unsigned bf16rne(float f) {          // round-to-nearest-even
    unsigned u = __float_as_uint(f);
    return (u + 0x7FFFu + ((u >> 16) & 1u)) >> 16;
}
static __device__ inline unsigned packbf(float lo, float hi) { // lo=ch 2l, hi=ch 2l+1
    return (bf16rne(hi) << 16) | bf16rne(lo);
}

// ---------------------------------------------------------------------------
// CSR build: histogram of dst (total + poly), two-level exclusive scan,
// scatter with poly edges placed FIRST within each node's segment.
// ---------------------------------------------------------------------------
__global__ void hist_kernel(const int* __restrict__ dst, const int* __restrict__ attr,
                            int* __restrict__ cnt, int* __restrict__ pcnt) {
    int i = blockIdx.x * blockDim.x + threadIdx.x;
    int stride = gridDim.x * blockDim.x;
    for (; i < N_EDGES; i += stride) {
        int d = dst[i];
        atomicAdd(&cnt[d], 1);
        if (attr[i] == 3) atomicAdd(&pcnt[d], 1);
    }
}

__device__ inline int wave_incl_scan(int v, int lane) {
#pragma unroll
    for (int off = 1; off < 64; off <<= 1) {
        int n = __shfl_up(v, off);
        if (lane >= off) v += n;
    }
    return v;
}

__global__ __launch_bounds__(1024) void scan1_kernel(const int* __restrict__ cnt,
                                                     int* __restrict__ excl,
                                                     int* __restrict__ bsum) {
    __shared__ int wsum[16];
    const int t = threadIdx.x, lane = t & 63, wid = t >> 6;
    const int i = blockIdx.x * 1024 + t;
    const int v = (i < N_NODES) ? cnt[i] : 0;
    int inc = wave_incl_scan(v, lane);
    if (lane == 63) wsum[wid] = inc;
    __syncthreads();
    if (t < 16) {
        int w = wsum[t];
#pragma unroll
        for (int off = 1; off < 16; off <<= 1) {
            int n = __shfl_up(w, off);
            if (t >= off) w += n;
        }
        wsum[t] = w;
    }
    __syncthreads();
    const int woff = (wid == 0) ? 0 : wsum[wid - 1];
    if (i < N_NODES) excl[i] = inc - v + woff;
    if (t == 0) bsum[blockIdx.x] = wsum[15];
}

__global__ void scan2_kernel(const int* __restrict__ bsum, int* __restrict__ bofs) {
    __shared__ int wsum[2];
    const int t = threadIdx.x, lane = t & 63, wid = t >> 6;
    const int v = (t < SCAN_BLOCKS) ? bsum[t] : 0;
    int inc = wave_incl_scan(v, lane);
    if (lane == 63) wsum[wid] = inc;
    __syncthreads();
    const int woff = (wid == 0) ? 0 : wsum[0];
    if (t < SCAN_BLOCKS) bofs[t] = inc - v + woff;
}

__global__ __launch_bounds__(1024) void scan3_kernel(const int* __restrict__ excl,
                                                     const int* __restrict__ bofs,
                                                     const int* __restrict__ pcnt,
                                                     int* __restrict__ row_off,
                                                     int* __restrict__ poly_end) {
    const int i = blockIdx.x * 1024 + threadIdx.x;
    if (i < N_NODES) {
        const int r = excl[i] + bofs[blockIdx.x];
        row_off[i]  = r;
        poly_end[i] = r + pcnt[i];
    }
    if (i == 0) row_off[N_NODES] = N_EDGES;
}

__global__ void scatter_kernel(const int* __restrict__ src, const int* __restrict__ dst,
                               const int* __restrict__ attr,
                               const int* __restrict__ row_off, const int* __restrict__ poly_end,
                               int* __restrict__ curP, int* __restrict__ curR,
                               int* __restrict__ pack) {
    int i = blockIdx.x * blockDim.x + threadIdx.x;
    int stride = gridDim.x * blockDim.x;
    for (; i < N_EDGES; i += stride) {
        int d = dst[i];
        int pos;
        if (attr[i] == 3) pos = row_off[d]  + atomicAdd(&curP[d], 1);
        else              pos = poly_end[d] + atomicAdd(&curR[d], 1);
        pack[pos] = src[i];  // order within a segment is nondeterministic; max is invariant
    }
}

// ---------------------------------------------------------------------------
// Input projection: h0 = relu(x @ W_in^T + b_in), plus a bf16 shadow h16 for
// the next layer's gather.  One wave per node; lane l owns channels (2l,2l+1).
// ---------------------------------------------------------------------------
__global__ void in_proj_kernel(const float* __restrict__ x, const float* __restrict__ Win,
                               const float* __restrict__ bin, float* __restrict__ h0,
                               unsigned* __restrict__ h16) {
    __shared__ float Wl[C_H * 11];
    for (int i = threadIdx.x; i < C_H * C_IN; i += blockDim.x) {
        int c = i / C_IN, k = i % C_IN;
        Wl[c * 11 + k] = Win[i];
    }
    __syncthreads();
    const int l = threadIdx.x & 63, wid = threadIdx.x >> 6;
    const int wave = blockIdx.x * 4 + wid, nw = gridDim.x * 4;
    const float2 bb = *reinterpret_cast<const float2*>(bin + 2 * l);
    for (int n = wave; n < N_NODES; n += nw) {
        float xr[C_IN];
#pragma unroll
        for (int k = 0; k < C_IN; ++k) xr[k] = x[n * C_IN + k];  // wave-uniform
        float a0 = bb.x, a1 = bb.y;
#pragma unroll
        for (int k = 0; k < C_IN; ++k) {
            a0 = fmaf(xr[k], Wl[(2 * l) * 11 + k], a0);
            a1 = fmaf(xr[k], Wl[(2 * l + 1) * 11 + k], a1);
        }
        a0 = fmaxf(a0, 0.f);
        a1 = fmaxf(a1, 0.f);
        *reinterpret_cast<float2*>(h0 + (size_t)n * C_H + 2 * l) = make_float2(a0, a1);
        h16[(size_t)n * 64 + l] = packbf(a0, a1);
    }
}

// ---------------------------------------------------------------------------
// Fused MPNN layer: bf16 gather-max -> fp32 GEMM -> LN -> residual ReLU.
// MODE 0: hop0  (hout+hout16, nf  = o*sg)
// MODE 1: hop1  (hout+hout16, nf += o*sg)
// MODE 2: hop2  (no hout; nf += o*sg, write nf16 (=hout16), v3 reduction)
// MODE 3: final (no writes; poly-only agg; v2 reduction; residual = nf)
//
// == R9 configuration verbatim (session best: 762 us) ==
// 1024-thread block = 16 waves, ONE LDS W copy (fp32, 64 KB, swizzle key
// (c>>1)&31 so lane l's rows 2l,2l+1 read conflict-free) + aggU 16 KB
// (packed bf16 agg) = 80 KB.
// Gather: ONE uint per lane per edge (channels 2l,2l+1 packed bf16); a wave
// load covers the full 256B row.  pk-u16 max (values >= 0).  Depth 8/4/2/1.
// NOTE: plain (cached) gather loads.  R13 tried __builtin_nontemporal_load
// here: -22% (mean degree 16 -> ~16x L1/L2 reuse per row; NT bypassed it).
// Session evidence: 7 configs (fp32/bf16 rows, 4096-16384 waves, VALU
// 14-58%, occupancy 18-43%) all deliver 8-10G random-row requests/s ->
// request-rate wall ~65 cyc/request/CU; this kernel sits within ~3% of it.
// ---------------------------------------------------------------------------
#define NPW 4
#define LWAVES 16

template <int MODE>
__global__ __launch_bounds__(1024) void layer_kernel(
    const float* __restrict__ hin, const unsigned* __restrict__ hin16,
    float* __restrict__ hout, unsigned* __restrict__ hout16,
    float* __restrict__ nf, const float* __restrict__ x,
    const int* __restrict__ row_off, const int* __restrict__ poly_end,
    const int* __restrict__ pack,
    const float* __restrict__ W, const float* __restrict__ bias,
    const float* __restrict__ gamma, const float* __restrict__ beta,
    const float* __restrict__ gate, float* __restrict__ out)
{
    __shared__ float    Wl[C_H * C_H];             // 64 KB, swizzle key (c>>1)&31
    __shared__ unsigned aggU[LWAVES][NPW * 64];    // 16 KB, packed bf16 agg rows

    for (int i = threadIdx.x; i < C_H * C_H; i += 1024) {
        int c = i >> 7, k = i & 127;
        Wl[(c << 7) + (k ^ ((c >> 1) & 31))] = W[i];   // conflict-free write
    }
    __syncthreads();

    const int l = threadIdx.x & 63, wid = threadIdx.x >> 6;
    const int swz = l & 31;
    const int row0 = (2 * l) << 7, row1 = (2 * l + 1) << 7;
    const int wave = blockIdx.x * LWAVES + wid, nw = gridDim.x * LWAVES;

    const float2 bb = *reinterpret_cast<const float2*>(bias  + 2 * l);
    const float2 gg = *reinterpret_cast<const float2*>(gamma + 2 * l);
    const float2 ee = *reinterpret_cast<const float2*>(beta  + 2 * l);
    float sg0 = 0.f, sg1 = 0.f;
    if (MODE <= 2) {
        const float2 gt = *reinterpret_cast<const float2*>(gate + 2 * l);
        sg0 = 1.f / (1.f + expf(-gt.x));
        sg1 = 1.f / (1.f + expf(-gt.y));
    }

    float red0 = 0.f, red1 = 0.f;                  // v2/v3 per-wave partial max (>= 0)

    const unsigned* __restrict__ hb16 = hin16 + l;

    for (int base = wave * NPW; base < N_NODES; base += nw * NPW) {
        bool anyp[NPW];
        // ---- aggregation: packed-bf16 CSR segment max, depth ladder 8/4/2/1 ----
#pragma unroll
        for (int j = 0; j < NPW; ++j) {
            const int n = base + j;
            unsigned m = 0u;                       // bf16 {0,0}; "no incoming" -> 0
            bool ap = false;
            if (n < N_NODES) {
                const int beg = row_off[n];
                const int end = (MODE == 3) ? poly_end[n] : row_off[n + 1];
                ap = (end > beg);
                int e = beg;
                for (; e + 8 <= end; e += 8) {
                    unsigned v[8];
#pragma unroll
                    for (int t = 0; t < 8; ++t)
                        v[t] = hb16[(size_t)pack[e + t] * 64];
#pragma unroll
                    for (int t = 0; t < 8; ++t) m = pkmax(m, v[t]);
                }
                for (; e + 4 <= end; e += 4) {
                    const unsigned v0 = hb16[(size_t)pack[e]     * 64];
                    const unsigned v1 = hb16[(size_t)pack[e + 1] * 64];
                    const unsigned v2 = hb16[(size_t)pack[e + 2] * 64];
                    const unsigned v3 = hb16[(size_t)pack[e + 3] * 64];
                    m = pkmax(m, pkmax(pkmax(v0, v1), pkmax(v2, v3)));
                }
                for (; e + 2 <= end; e += 2) {
                    const unsigned v0 = hb16[(size_t)pack[e]     * 64];
                    const unsigned v1 = hb16[(size_t)pack[e + 1] * 64];
                    m = pkmax(m, pkmax(v0, v1));
                }
                if (e < end) m = pkmax(m, hb16[(size_t)pack[e] * 64]);
            }
            anyp[j] = ap;
            aggU[wid][j * 64 + l] = m;             // wave-private, no barrier needed
        }

        // ---- GEMM: out[c] = sum_k agg[k] * W[c][k], 2 cols per packed agg ----
        float acc[NPW][2];
#pragma unroll
        for (int j = 0; j < NPW; ++j) { acc[j][0] = 0.f; acc[j][1] = 0.f; }
#pragma unroll 4
        for (int t = 0; t < 64; ++t) {
            const int c0 = (2 * t) ^ swz, c1 = (2 * t + 1) ^ swz;  // swizzled cols
            const float w00 = Wl[row0 + c0], w01 = Wl[row0 + c1];  // W[2l][2t], W[2l][2t+1]
            const float w10 = Wl[row1 + c0], w11 = Wl[row1 + c1];  // W[2l+1][..]
#pragma unroll
            for (int j = 0; j < NPW; ++j) {
                const unsigned u = aggU[wid][j * 64 + t];          // broadcast
                const float a0 = __uint_as_float(u << 16);         // ch 2t
                const float a1 = __uint_as_float(u & 0xFFFF0000u); // ch 2t+1
                acc[j][0] = fmaf(a1, w01, fmaf(a0, w00, acc[j][0]));
                acc[j][1] = fmaf(a1, w11, fmaf(a0, w10, acc[j][1]));
            }
        }

        // ---- epilogue: bias, LN, residual relu, nf/v-reductions ----
#pragma unroll
        for (int j = 0; j < NPW; ++j) {
            const int n = base + j;
            if (n < N_NODES) {               // wave-uniform branch
                float h0 = acc[j][0] + bb.x, h1 = acc[j][1] + bb.y;  // ch 2l, 2l+1
                float s = h0 + h1, q = h0 * h0 + h1 * h1;
#pragma unroll
                for (int m2 = 1; m2 < 64; m2 <<= 1) {
                    s += __shfl_xor(s, m2);
                    q += __shfl_xor(q, m2);
                }
                const float mu  = s * (1.f / 128.f);
                const float var = q * (1.f / 128.f) - mu * mu;   // biased var
                const float rs  = rsqrtf(var + LN_EPS);
                const float2 r = *reinterpret_cast<const float2*>(hin + (size_t)n * C_H + 2 * l);
                const float o0 = fmaxf((h0 - mu) * rs * gg.x + ee.x + r.x, 0.f);
                const float o1 = fmaxf((h1 - mu) * rs * gg.y + ee.y + r.y, 0.f);
                if (MODE <= 1) {
                    *reinterpret_cast<float2*>(hout + (size_t)n * C_H + 2 * l) = make_float2(o0, o1);
                    hout16[(size_t)n * 64 + l] = packbf(o0, o1);
                }
                if (MODE == 0) {
                    *reinterpret_cast<float2*>(nf + (size_t)n * C_H + 2 * l) =
                        make_float2(o0 * sg0, o1 * sg1);
                } else if (MODE == 1) {
                    float2* p = reinterpret_cast<float2*>(nf + (size_t)n * C_H + 2 * l);
                    float2 v = *p;
                    v.x += o0 * sg0; v.y += o1 * sg1;
                    *p = v;
                } else if (MODE == 2) {
                    float2* p = reinterpret_cast<float2*>(nf + (size_t)n * C_H + 2 * l);
                    float2 v = *p;
                    const float f0 = v.x + o0 * sg0, f1 = v.y + o1 * sg1;
                    *p = make_float2(f0, f1);
                    hout16[(size_t)n * 64 + l] = packbf(f0, f1);   // nf16 for MODE 3
                    if (x[(size_t)n * C_IN] <= 0.1f) {             // rem = !(x0 > 0.1)
                        red0 = fmaxf(red0, f0);
                        red1 = fmaxf(red1, f1);
                    }
                } else {                                            // MODE 3
                    if (anyp[j]) {                                  // sink node
                        red0 = fmaxf(red0, o0);
                        red1 = fmaxf(red1, o1);
                    }
                }
            }
        }
    }

    if (MODE >= 2) {
        __syncthreads();
        float* red = reinterpret_cast<float*>(&aggU[0][0]);  // alias (16 KB >= 8 KB)
        *reinterpret_cast<float2*>(&red[wid * 128 + 2 * l]) = make_float2(red0, red1);
        __syncthreads();
        if (threadIdx.x < 128) {
            const int c = threadIdx.x;
            float m = red[c];
#pragma unroll
            for (int w = 1; w < LWAVES; ++w) m = fmaxf(m, red[w * 128 + c]);
            float* o = out + (MODE == 3 ? 0 : 128);
            atomicMax(reinterpret_cast<int*>(o + c), __float_as_int(m));  // m >= 0
        }
    }
}

// ---------------------------------------------------------------------------
extern "C" void kernel_launch(void* const* d_in, const int* in_sizes, int n_in,
                              void* d_out, int out_size, void* d_ws, size_t ws_size,
                              hipStream_t stream) {
    const float* x      = (const float*)d_in[0];
    const float* W_in   = (const float*)d_in[1];
    const float* b_in   = (const float*)d_in[2];
    const float* hop_W  = (const float*)d_in[3];
    const float* hop_b  = (const float*)d_in[4];
    const float* hop_g  = (const float*)d_in[5];
    const float* hop_be = (const float*)d_in[6];
    const float* gates  = (const float*)d_in[7];
    const float* fW     = (const float*)d_in[8];
    const float* fb     = (const float*)d_in[9];
    const float* fg     = (const float*)d_in[10];
    const float* fbe    = (const float*)d_in[11];
    const int*   eidx   = (const int*)d_in[12];
    const int*   eattr  = (const int*)d_in[13];
    float* out = (float*)d_out;

    char* ws = (char*)d_ws;
    size_t off = 0;
    auto alloc = [&](size_t bytes) {
        char* p = ws + off;
        off = (off + bytes + 255) & ~(size_t)255;
        return p;
    };
    const size_t npad = ((size_t)N_NODES * 4 + 255) & ~(size_t)255;
    int*      cnt     = (int*)alloc((size_t)N_NODES * 4);
    int*      pcnt    = (int*)alloc((size_t)N_NODES * 4);
    int*      curP    = (int*)alloc((size_t)N_NODES * 4);
    int*      curR    = (int*)alloc((size_t)N_NODES * 4);
    int*      excl    = (int*)alloc((size_t)N_NODES * 4);
    int*      bsum    = (int*)alloc((size_t)SCAN_BLOCKS * 4);
    int*      bofs    = (int*)alloc((size_t)SCAN_BLOCKS * 4);
    int*      row_off = (int*)alloc((size_t)(N_NODES + 1) * 4);
    int*      polyend = (int*)alloc((size_t)N_NODES * 4);
    int*      pack    = (int*)alloc((size_t)N_EDGES * 4);
    float*    hA      = (float*)alloc((size_t)N_NODES * C_H * 4);
    float*    hB      = (float*)alloc((size_t)N_NODES * C_H * 4);
    float*    nf      = (float*)alloc((size_t)N_NODES * C_H * 4);
    unsigned* hA16    = (unsigned*)alloc((size_t)N_NODES * 64 * 4);
    unsigned* hB16    = (unsigned*)alloc((size_t)N_NODES * 64 * 4);
    unsigned* nf16    = hB16;   // alias: hB16 is dead after MODE 1 reads it
    (void)ws_size;

    const int* src = eidx;
    const int* dst = eidx + N_EDGES;

    // cnt..curR are contiguous padded allocs: one memset covers all four
    hipMemsetAsync(cnt, 0, npad * 4, stream);
    hipMemsetAsync(d_out, 0, 256 * 4, stream);   // v2/v3 accumulate via atomicMax (vals >= 0)

    hist_kernel<<<2048, 256, 0, stream>>>(dst, eattr, cnt, pcnt);
    scan1_kernel<<<SCAN_BLOCKS, 1024, 0, stream>>>(cnt, excl, bsum);
    scan2_kernel<<<1, 128, 0, stream>>>(bsum, bofs);
    scan3_kernel<<<SCAN_BLOCKS, 1024, 0, stream>>>(excl, bofs, pcnt, row_off, polyend);
    scatter_kernel<<<2048, 256, 0, stream>>>(src, dst, eattr, row_off, polyend, curP, curR, pack);
    in_proj_kernel<<<2048, 256, 0, stream>>>(x, W_in, b_in, hA, hA16);

    layer_kernel<0><<<512, 1024, 0, stream>>>(hA, hA16, hB, hB16, nf, x, row_off, polyend, pack,
                                              hop_W + 0 * C_H * C_H, hop_b + 0 * C_H,
                                              hop_g + 0 * C_H, hop_be + 0 * C_H,
                                              gates + 0 * C_H, out);
    layer_kernel<1><<<512, 1024, 0, stream>>>(hB, hB16, hA, hA16, nf, x, row_off, polyend, pack,
                                              hop_W + 1 * C_H * C_H, hop_b + 1 * C_H,
                                              hop_g + 1 * C_H, hop_be + 1 * C_H,
                                              gates + 1 * C_H, out);
    layer_kernel<2><<<512, 1024, 0, stream>>>(hA, hA16, nullptr, nf16, nf, x, row_off, polyend, pack,
                                              hop_W + 2 * C_H * C_H, hop_b + 2 * C_H,
                                              hop_g + 2 * C_H, hop_be + 2 * C_H,
                                              gates + 2 * C_H, out);
    layer_kernel<3><<<512, 1024, 0, stream>>>(nf, nf16, nullptr, nullptr, nullptr, x, row_off, polyend, pack,
                                              fW, fb, fg, fbe, nullptr, out);
}